// Round 2
// baseline (1048.998 us; speedup 1.0000x reference)
//
#include <hip/hip_runtime.h>
#include <stdint.h>
#include <stddef.h>

#define DEVINL static __device__ __forceinline__

typedef __attribute__((ext_vector_type(8))) short  bfrag;   // 8x bf16 (bits)
typedef __attribute__((ext_vector_type(4))) float  facc;    // MFMA accumulator

DEVINL uint16_t f2b(float f){
  uint32_t u = __float_as_uint(f);
  return (uint16_t)((u + 0x7fffu + ((u >> 16) & 1u)) >> 16);   // RNE
}
DEVINL float b2f(uint16_t b){ return __uint_as_float(((uint32_t)b) << 16); }

DEVINL facc MFMA(bfrag a, bfrag b, facc c){
  return __builtin_amdgcn_mfma_f32_16x16x32_bf16(a, b, c, 0, 0, 0);
}

// async global->LDS, 16B per lane; LDS dest = wave-uniform base + lane*16
DEVINL void gload16(const void* g, void* l){
  __builtin_amdgcn_global_load_lds(
      (const __attribute__((address_space(1))) uint32_t*)g,
      (__attribute__((address_space(3))) uint32_t*)l, 16, 0, 0);
}

// ---------------- generic f32 -> bf16 convert ----------------
__global__ void k_f2b(const float* __restrict__ s, uint16_t* __restrict__ d, int n){
  int i = blockIdx.x*256 + threadIdx.x;
  int st = gridDim.x*256;
  for(; i<n; i+=st) d[i] = f2b(s[i]);
}

// ---------------- Legendre tmat [8][19] ----------------
__global__ void k_tmat(float* tm){
  int t = threadIdx.x;
  if(t < 19){
    float tv = (float)(t - 6) / 12.0f;
    float Pm = 1.0f, Pc = tv;
    tm[0*19+t] = Pm * sqrtf(0.5f);
    tm[1*19+t] = Pc * sqrtf(1.5f);
    for(int n=1; n<7; n++){
      float Pn = ((float)(2*n+1)*tv*Pc - (float)n*Pm) / (float)(n+1);
      Pm = Pc; Pc = Pn;
      tm[(n+1)*19+t] = Pc * sqrtf((float)(2*(n+1)+1) * 0.5f);
    }
  }
}

// ---------------- LSTM weight prep ----------------
// Wc[256][96] bf16 : [0..63]=Whh row, [64..68]=Wih@state_fc_W (folded), [69..95]=0
// be[256] = bih+bhh+Wih@state_fc_b ; encWb[64][64] bf16
__global__ void k_lstm_prep(const float* __restrict__ Wih, const float* __restrict__ Whh,
                            const float* __restrict__ bih, const float* __restrict__ bhh,
                            const float* __restrict__ sW, const float* __restrict__ sb,
                            const float* __restrict__ encW,
                            uint16_t* __restrict__ Wc, float* __restrict__ be,
                            uint16_t* __restrict__ encWb){
  int n = threadIdx.x;
  for(int k=0;k<64;k++) Wc[n*96+k] = f2b(Whh[n*64+k]);
  for(int k5=0;k5<5;k5++){
    float s = 0.f;
    for(int j=0;j<64;j++) s += Wih[n*64+j]*sW[j*5+k5];
    Wc[n*96+64+k5] = f2b(s);
  }
  for(int k=69;k<96;k++) Wc[n*96+k] = 0;
  float s = 0.f;
  for(int j=0;j<64;j++) s += Wih[n*64+j]*sb[j];
  be[n] = s + bih[n] + bhh[n];
  if(n < 64){
    for(int k=0;k<64;k++) encWb[n*64+k] = f2b(encW[n*64+k]);
  }
}

// ---------------- LSTM: 32 sequences / block, MFMA gates ----------------
// blocks 0..3: ego (128 seqs) -> egoT[:,512:576], feat[:,1024:1088]
// blocks 4..131: agents (4096 seqs) -> atomic scatter into grid [128][196][64]
__global__ __launch_bounds__(256) void k_lstm(
    const float* __restrict__ ego_seq, const float* __restrict__ ag_seq,
    const int* __restrict__ ego_len, const int* __restrict__ ag_len,
    const int* __restrict__ grid_pos,
    const uint16_t* __restrict__ Wc, const float* __restrict__ be,
    const uint16_t* __restrict__ encWb, const float* __restrict__ encB,
    float* __restrict__ agrid, uint16_t* __restrict__ egoT, uint16_t* __restrict__ feat)
{
  __shared__ __align__(16) uint16_t A[32*96];   // [seq][k] : k<64 h, 64..68 x_t, 69..95 zero
  __shared__ float Xf[32*160];                  // raw seq f32 [32][32][5]
  __shared__ int   idxs[32];

  int t = threadIdx.x, w = t>>6, l = t&63;
  int blk = blockIdx.x;
  bool isEgo = blk < 4;
  int seq0 = isEgo ? blk*32 : (blk-4)*32;
  const float* seqp = (isEgo ? ego_seq : ag_seq) + (size_t)seq0*160;

  for(int i=t;i<32*160;i+=256) Xf[i] = seqp[i];
  if(t < 32){
    int L = isEgo ? ego_len[seq0+t] : ag_len[seq0+t];
    if(L < 1) L = 1;
    idxs[t] = L-1;
  }
  for(int i=t;i<32*96;i+=256) A[i] = 0;

  // B fragments: wave w owns col-tiles {w, 4+w, 8+w, 12+w}  (i,f,g,o for units w*16..w*16+15)
  bfrag bf[4][3];
  float be4[4];
  for(int ct=0;ct<4;ct++){
    int n = (ct*4+w)*16 + (l&15);
    for(int ks=0;ks<3;ks++)
      bf[ct][ks] = *(const bfrag*)(Wc + n*96 + ks*32 + (l>>4)*8);
    be4[ct] = be[n];
  }
  float cst[8], hl[8];
  for(int i=0;i<8;i++){ cst[i]=0.f; hl[i]=0.f; }
  __syncthreads();
  int myidx[8];
  for(int rt=0;rt<2;rt++) for(int r=0;r<4;r++){
    int s = rt*16 + (l>>4)*4 + r;
    myidx[rt*4+r] = idxs[s];
  }

  for(int st=0; st<32; st++){
    if(t < 160){ int s=t/5, kk=t%5; A[s*96+64+kk] = f2b(Xf[s*160 + st*5 + kk]); }
    __syncthreads();
    facc acc[2][4];
    for(int rt=0;rt<2;rt++) for(int ct=0;ct<4;ct++) acc[rt][ct] = facc{0.f,0.f,0.f,0.f};
    #pragma unroll
    for(int ks=0;ks<3;ks++){
      bfrag aA[2];
      #pragma unroll
      for(int rt=0;rt<2;rt++)
        aA[rt] = *(const bfrag*)(A + (rt*16+(l&15))*96 + ks*32 + (l>>4)*8);
      #pragma unroll
      for(int rt=0;rt<2;rt++)
        #pragma unroll
        for(int ct=0;ct<4;ct++)
          acc[rt][ct] = MFMA(aA[rt], bf[ct][ks], acc[rt][ct]);
    }
    __syncthreads();   // all A reads done before h overwrite
    #pragma unroll
    for(int rt=0;rt<2;rt++) for(int r=0;r<4;r++){
      int cell = rt*4+r;
      int s = rt*16 + (l>>4)*4 + r;
      float gi = acc[rt][0][r] + be4[0];
      float gf = acc[rt][1][r] + be4[1];
      float gg = acc[rt][2][r] + be4[2];
      float go = acc[rt][3][r] + be4[3];
      float si = 1.f/(1.f+__expf(-gi));
      float sf = 1.f/(1.f+__expf(-gf));
      float so = 1.f/(1.f+__expf(-go));
      float tg = tanhf(gg);
      float c2 = sf*cst[cell] + si*tg;
      cst[cell] = c2;
      float hn = so*tanhf(c2);
      A[s*96 + w*16 + (l&15)] = f2b(hn);
      if(st == myidx[cell]) hl[cell] = hn;
    }
  }
  __syncthreads();
  for(int rt=0;rt<2;rt++) for(int r=0;r<4;r++){
    int s = rt*16 + (l>>4)*4 + r;
    A[s*96 + w*16 + (l&15)] = f2b(hl[rt*4+r]);
  }
  __syncthreads();
  // enc_fc: out[s][n] = hl[s] . encW[n] + encB[n];  wave w -> n tile w
  bfrag eb[2];
  for(int ks=0;ks<2;ks++)
    eb[ks] = *(const bfrag*)(encWb + (w*16+(l&15))*64 + ks*32 + (l>>4)*8);
  facc ea[2]; ea[0] = facc{0.f,0.f,0.f,0.f}; ea[1] = facc{0.f,0.f,0.f,0.f};
  for(int ks=0;ks<2;ks++){
    for(int rt=0;rt<2;rt++){
      bfrag aA = *(const bfrag*)(A + (rt*16+(l&15))*96 + ks*32 + (l>>4)*8);
      ea[rt] = MFMA(aA, eb[ks], ea[rt]);
    }
  }
  int n = w*16 + (l&15);
  float bn_ = encB[n];
  for(int rt=0;rt<2;rt++) for(int r=0;r<4;r++){
    int s = rt*16 + (l>>4)*4 + r;
    float v = ea[rt][r] + bn_;
    int gs = seq0 + s;
    if(isEgo){
      egoT[(size_t)gs*576 + 512 + n] = f2b(v);
      feat[(size_t)gs*1088 + 1024 + n] = f2b(v);
    } else {
      int py = grid_pos[gs*2+0], px = grid_pos[gs*2+1];
      atomicAdd(&agrid[((size_t)(gs>>5)*196 + py*14 + px)*64 + n], v);
    }
  }
}

// ---------------- pack conv1 input: NCHW f32 (+grid NHWC f32) -> padded NHWC bf16 ----------------
// Xp [128][16][16][1088], border pre-zeroed by memset
__global__ void k_packx(const float* __restrict__ cnn, const float* __restrict__ agrid,
                        uint16_t* __restrict__ Xp)
{
  __shared__ float tile[32*200];
  int b = blockIdx.x, ch = blockIdx.y, t = threadIdx.x;
  if(ch < 32){
    int c0 = ch*32;
    for(int i=t;i<32*196;i+=256){
      int ci = i/196, s = i%196;
      tile[ci*200+s] = cnn[((size_t)b*1024 + c0+ci)*196 + s];
    }
    __syncthreads();
    for(int i=t;i<32*196;i+=256){
      int s = i>>5, ci = i&31;
      int y = s/14, x = s%14;
      Xp[(((size_t)b*16 + y+1)*16 + x+1)*1088 + c0 + ci] = f2b(tile[ci*200+s]);
    }
  } else {
    int j0 = (ch-32)*32;
    for(int i=t;i<32*196;i+=256){
      int s = i>>5, ji = i&31;
      int y = s/14, x = s%14;
      Xp[(((size_t)b*16 + y+1)*16 + x+1)*1088 + 1024 + j0 + ji] =
          f2b(agrid[((size_t)b*196 + s)*64 + j0 + ji]);
    }
  }
}

// ---------------- pack conv weights OIHW f32 -> [dydx][O][C] bf16 (B^T layout) ----------------
__global__ void k_packw(const float* __restrict__ W, uint16_t* __restrict__ Wp, int O, int C)
{
  int o = blockIdx.x;
  int c = blockIdx.y*64 + threadIdx.x;
  const float* src = W + ((size_t)o*C + c)*9;
  float v[9];
  #pragma unroll
  for(int d=0;d<9;d++) v[d] = src[d];
  #pragma unroll
  for(int d=0;d<9;d++)
    Wp[((size_t)d*O + o)*C + c] = f2b(v[d]);
}

// ---------------- implicit-GEMM conv (m97-style 128x128, BK=64) ----------------
// MODE 0: conv1  (A=Xp padded NHWC, C=1088, out padded Y1p)
// MODE 1: conv2  (A=Y1p padded, C=512, stride 2, out [6272][512])
// MODE 2: kv 1x1 (A=Y2 [6272][512], out [6272][2048])
template<int MODE>
__global__ __launch_bounds__(256) void k_conv(
    const uint16_t* __restrict__ Ain, const uint16_t* __restrict__ Wb,
    uint16_t* __restrict__ Out)
{
  constexpr int CB  = (MODE==0) ? 1088 : 512;
  constexpr int NB  = (MODE==2) ? 2048 : 512;
  constexpr int NDY = (MODE==2) ? 1 : 9;
  constexpr int NCC = (MODE==0) ? 17 : 8;

  __shared__ __align__(16) uint16_t As[128*64];
  __shared__ __align__(16) uint16_t Bs[128*64];
  __shared__ int rowOff[128];
  __shared__ int outOff[128];

  int t = threadIdx.x, w = t>>6, l = t&63;
  int n0 = blockIdx.x*128, m0 = blockIdx.y*128;

  if(t < 128){
    int m = m0 + t, ro, oo;
    if(MODE==0){
      int b = m/196, s = m%196, y = s/14, x = s%14;
      ro = ((b*16 + y)*16 + x)*1088;
      oo = ((b*16 + y+1)*16 + (x+1))*512;
    } else if(MODE==1){
      int b = m/49, s = m%49, y = s/7, x = s%7;
      ro = ((b*16 + 2*y)*16 + 2*x)*512;
      oo = m*512;
    } else {
      ro = m*512; oo = m*2048;
    }
    rowOff[t] = ro; outOff[t] = oo;
  }
  __syncthreads();

  facc acc[4][4];
  for(int i=0;i<4;i++) for(int j=0;j<4;j++) acc[i][j] = facc{0.f,0.f,0.f,0.f};
  int wm = w>>1, wn = w&1;

  for(int kidx=0; kidx<NDY*NCC; kidx++){
    int dydx = kidx/NCC, c0 = (kidx%NCC)*64;
    int dy = dydx/3, dx = dydx%3;
    int aOff = (MODE==2) ? c0 : ((dy*16+dx)*CB + c0);
    // stage A tile [128 rows][64 k] bf16
    #pragma unroll
    for(int p=0;p<4;p++){
      int r = w*32 + p*8 + (l>>3);
      const uint16_t* g = Ain + rowOff[r] + aOff + (l&7)*8;
      gload16(g, (char*)As + w*4096 + p*1024);
    }
    // stage B tile [128 n][64 k]
    #pragma unroll
    for(int p=0;p<4;p++){
      int r = w*32 + p*8 + (l>>3);
      const uint16_t* g = Wb + ((size_t)(dydx*NB + n0 + r))*CB + c0 + (l&7)*8;
      gload16(g, (char*)Bs + w*4096 + p*1024);
    }
    __syncthreads();
    #pragma unroll
    for(int ks=0;ks<2;ks++){
      bfrag a[4], b[4];
      #pragma unroll
      for(int i=0;i<4;i++)
        a[i] = *(const bfrag*)(As + (wm*64 + i*16 + (l&15))*64 + ks*32 + (l>>4)*8);
      #pragma unroll
      for(int j=0;j<4;j++)
        b[j] = *(const bfrag*)(Bs + (wn*64 + j*16 + (l&15))*64 + ks*32 + (l>>4)*8);
      #pragma unroll
      for(int i=0;i<4;i++)
        #pragma unroll
        for(int j=0;j<4;j++)
          acc[i][j] = MFMA(a[i], b[j], acc[i][j]);
    }
    __syncthreads();
  }
  #pragma unroll
  for(int i=0;i<4;i++)
    #pragma unroll
    for(int j=0;j<4;j++){
      int n = n0 + wn*64 + j*16 + (l&15);
      #pragma unroll
      for(int r=0;r<4;r++){
        int mr = wm*64 + i*16 + (l>>4)*4 + r;
        Out[(size_t)outOff[mr] + n] = f2b(acc[i][j][r]);
      }
    }
}

// ---------------- BN batch stats (sum/sumsq per channel, 512 ch, atomics) ----------------
template<int PAD>
__global__ void k_bnstats(const uint16_t* __restrict__ Y, float* __restrict__ stats, int M)
{
  int t = threadIdx.x;
  int m0 = blockIdx.x*256;
  float s0=0,s1=0,q0=0,q1=0;
  for(int i=0;i<256;i++){
    int m = m0+i; if(m>=M) break;
    size_t off;
    if(PAD){ int b=m/196, s=m%196, y=s/14, x=s%14; off = (((size_t)b*16+y+1)*16 + x+1)*512; }
    else off = (size_t)m*512;
    uint32_t u = *(const uint32_t*)(Y + off + 2*t);
    float a = b2f((uint16_t)u), c = b2f((uint16_t)(u>>16));
    s0+=a; q0+=a*a; s1+=c; q1+=c*c;
  }
  atomicAdd(&stats[4*t+0], s0);
  atomicAdd(&stats[4*t+1], q0);
  atomicAdd(&stats[4*t+2], s1);
  atomicAdd(&stats[4*t+3], q1);
}

// ---------------- BN apply + ReLU in-place; conv2 variant extracts center into egoT/feat ----------------
template<int PAD>
__global__ void k_bnapply(uint16_t* __restrict__ Y, const float* __restrict__ stats,
                          const float* __restrict__ gg, const float* __restrict__ bb,
                          int M, float invM,
                          uint16_t* __restrict__ egoT, uint16_t* __restrict__ feat)
{
  int t = threadIdx.x;
  int m0 = blockIdx.x*8;
  float mu0 = stats[4*t+0]*invM, mu1 = stats[4*t+2]*invM;
  float v0 = stats[4*t+1]*invM - mu0*mu0, v1 = stats[4*t+3]*invM - mu1*mu1;
  float sc0 = gg[2*t]  *rsqrtf(v0+1e-5f), sc1 = gg[2*t+1]*rsqrtf(v1+1e-5f);
  float sh0 = bb[2*t]   - mu0*sc0,        sh1 = bb[2*t+1] - mu1*sc1;
  for(int i=0;i<8;i++){
    int m = m0+i; if(m>=M) break;
    size_t off;
    if(PAD){ int b=m/196, s=m%196, y=s/14, x=s%14; off = (((size_t)b*16+y+1)*16 + x+1)*512; }
    else off = (size_t)m*512;
    uint32_t u = *(const uint32_t*)(Y + off + 2*t);
    float a = fmaxf(b2f((uint16_t)u)*sc0 + sh0, 0.f);
    float c = fmaxf(b2f((uint16_t)(u>>16))*sc1 + sh1, 0.f);
    uint32_t pu = (uint32_t)f2b(a) | ((uint32_t)f2b(c)<<16);
    *(uint32_t*)(Y + off + 2*t) = pu;
    if(!PAD && (m%49)==24){
      int b = m/49;
      *(uint32_t*)(egoT + (size_t)b*576 + 2*t) = pu;
      *(uint32_t*)(feat + (size_t)b*1088 + 512 + 2*t) = pu;
    }
  }
}

// ---------------- small-M GEMM (M=128), no LDS: C[m][n] = A[m][:] . B[n][:] ----------------
// flags: 1 = relu, 2 = f32 output (else bf16)
__global__ __launch_bounds__(256) void k_sgemm(
    const uint16_t* __restrict__ A, int lda,
    const uint16_t* __restrict__ B, int ldb,
    const float* __restrict__ bias,
    void* __restrict__ C, int ldc,
    int N, int K, int flags)
{
  int t = threadIdx.x, w = t>>6, l = t&63;
  int nt = blockIdx.x*4 + w;
  int n  = nt*16 + (l&15);
  int m0 = blockIdx.y*16;
  bool nv = n < N;
  facc acc = facc{0.f,0.f,0.f,0.f};
  for(int k=0;k<K;k+=32){
    bfrag af = *(const bfrag*)(A + (size_t)(m0+(l&15))*lda + k + (l>>4)*8);
    bfrag bf_ = {0,0,0,0,0,0,0,0};
    if(nv) bf_ = *(const bfrag*)(B + (size_t)n*ldb + k + (l>>4)*8);
    acc = MFMA(af, bf_, acc);
  }
  if(nv){
    float bv = bias ? bias[n] : 0.f;
    #pragma unroll
    for(int r=0;r<4;r++){
      int m = m0 + (l>>4)*4 + r;
      float v = acc[r] + bv;
      if(flags & 1) v = fmaxf(v, 0.f);
      if(flags & 2) ((float*)C)[(size_t)m*ldc + n] = v;
      else ((uint16_t*)C)[(size_t)m*ldc + n] = f2b(v);
    }
  }
}

// ---------------- attention: one wave per (b,h); ring handled analytically ----------------
__global__ __launch_bounds__(256) void k_attn(
    const float* __restrict__ q, const uint16_t* __restrict__ kv,
    uint16_t* __restrict__ o)
{
  int t = threadIdx.x, w = t>>6, l = t&63;
  int idx = blockIdx.x*4 + w;          // b*16+h
  int b = idx>>4, h = idx&15;
  float qf = q[(size_t)b*1024 + h*64 + l];
  const uint16_t* kp = kv + (size_t)b*49*2048 + h*64 + l;
  float eo = 0.f;
  for(int g=0; g<49; g++){
    float p = qf * b2f(kp[(size_t)g*2048]);
    for(int s=32;s>0;s>>=1) p += __shfl_xor(p, s);
    if(l == g) eo = p;
  }
  float e = (l<49) ? eo*(1.f/32.f) : -1e30f;
  float mx = e;
  for(int s=32;s>0;s>>=1) mx = fmaxf(mx, __shfl_xor(mx, s));
  mx = fmaxf(mx, 0.f);                          // 32 ring slots have energy 0
  float p = (l<49) ? __expf(e-mx) : 0.f;
  float den = p;
  for(int s=32;s>0;s>>=1) den += __shfl_xor(den, s);
  den += 32.f*__expf(-mx);
  const uint16_t* vp = kv + (size_t)b*49*2048 + 1024 + h*64 + l;
  float accv = 0.f;
  for(int g=0; g<49; g++){
    float pg = __shfl(p, g);
    accv += pg * b2f(vp[(size_t)g*2048]);
  }
  o[(size_t)b*1024 + h*64 + l] = f2b(accv/den);
}

// ---------------- trajectory: d2[b][25][16] @ tmat -> out [b][25][19][2] ----------------
__global__ void k_traj(const float* __restrict__ d2, const float* __restrict__ tm,
                       float* __restrict__ out)
{
  int i = blockIdx.x*256 + threadIdx.x;
  if(i >= 3200) return;
  const float* dp = d2 + (size_t)i*16;
  float cx[8], cy[8];
  #pragma unroll
  for(int j=0;j<8;j++){ cx[j]=dp[j]; cy[j]=dp[8+j]; }
  float* op = out + (size_t)i*38;
  for(int tt=0;tt<19;tt++){
    float x=0.f, y=0.f;
    #pragma unroll
    for(int j=0;j<8;j++){ float tv = tm[j*19+tt]; x += cx[j]*tv; y += cy[j]*tv; }
    op[tt*2+0]=x; op[tt*2+1]=y;
  }
}

// ======================= host =======================
extern "C" void kernel_launch(void* const* d_in, const int* in_sizes, int n_in,
                              void* d_out, int out_size, void* d_ws, size_t ws_size,
                              hipStream_t stream)
{
  const float* cnn      = (const float*)d_in[0];
  const float* ego_seq  = (const float*)d_in[1];
  const float* ag_seq   = (const float*)d_in[2];
  const int*   ego_len  = (const int*)d_in[3];
  const int*   ag_len   = (const int*)d_in[4];
  const int*   grid_pos = (const int*)d_in[5];
  const float* sW  = (const float*)d_in[6];
  const float* sb  = (const float*)d_in[7];
  const float* Wih = (const float*)d_in[8];
  const float* Whh = (const float*)d_in[9];
  const float* bih = (const float*)d_in[10];
  const float* bhh = (const float*)d_in[11];
  const float* encW = (const float*)d_in[12];
  const float* encB = (const float*)d_in[13];
  const float* conv1W = (const float*)d_in[14];
  const float* bn1g = (const float*)d_in[15];
  const float* bn1b = (const float*)d_in[16];
  const float* conv2W = (const float*)d_in[17];
  const float* bn2g = (const float*)d_in[18];
  const float* bn2b = (const float*)d_in[19];
  const float* qWf  = (const float*)d_in[20];
  const float* kWf  = (const float*)d_in[21];
  const float* vWf  = (const float*)d_in[22];
  const float* aoW  = (const float*)d_in[23];
  const float* aoB  = (const float*)d_in[24];
  const float* clsWf = (const float*)d_in[25];
  const float* clsB  = (const float*)d_in[26];
  const float* d1Wf  = (const float*)d_in[27];
  const float* d1B   = (const float*)d_in[28];
  const float* d2Wf  = (const float*)d_in[29];
  const float* d2B   = (const float*)d_in[30];

  char* ws = (char*)d_ws;
  const size_t XP_OFF   = 0;                 // 71,303,168  (also aliased below after conv1)
  const size_t KV_OFF   = 0;                 // 25,690,112  (alias: after Xp dead)
  const size_t Y2_OFF   = 29360128;          // 6,422,528   (alias inside Xp region)
  const size_t Y1P_OFF  = 71303168;          // 33,554,432
  const size_t WP1_OFF  = 104857600;         // 10,027,008
  const size_t WP2_OFF  = 114884608;         // 4,718,592
  const size_t WKV_OFF  = 119603200;         // 2,097,152
  const size_t QW_OFF   = 121700352;         // 1,179,648
  const size_t AOW_OFF  = 122880000;         // 1,048,576
  const size_t CLSW_OFF = 123928576;         // 54,400
  const size_t D1W_OFF  = 123982976;         // 557,056
  const size_t D2W_OFF  = 124540032;         // 204,800
  const size_t GRID_OFF = 124744832;         // 6,422,528
  const size_t EGOT_OFF = 131167360;         // 147,456
  const size_t FEAT_OFF = 131314816;         // 278,528
  const size_t QBUF_OFF = 131593344;         // 524,288
  const size_t OBUF_OFF = 132117632;         // 262,144
  const size_t D1_OFF   = 132379776;         // 65,536
  const size_t D2_OFF   = 132445312;         // 204,800
  const size_t WC_OFF   = 132650112;         // 49,152
  const size_t BE_OFF   = 132699264;         // 1,024
  const size_t ENCW_OFF = 132700288;         // 8,192
  const size_t TMAT_OFF = 132708480;         // 608
  const size_t ST1_OFF  = 132709120;         // 4,096
  const size_t ST2_OFF  = 132713216;         // 4,096

  uint16_t* XP   = (uint16_t*)(ws + XP_OFF);
  uint16_t* KV   = (uint16_t*)(ws + KV_OFF);
  uint16_t* Y2   = (uint16_t*)(ws + Y2_OFF);
  uint16_t* Y1P  = (uint16_t*)(ws + Y1P_OFF);
  uint16_t* WP1  = (uint16_t*)(ws + WP1_OFF);
  uint16_t* WP2  = (uint16_t*)(ws + WP2_OFF);
  uint16_t* WKV  = (uint16_t*)(ws + WKV_OFF);
  uint16_t* QW   = (uint16_t*)(ws + QW_OFF);
  uint16_t* AOW  = (uint16_t*)(ws + AOW_OFF);
  uint16_t* CLSW = (uint16_t*)(ws + CLSW_OFF);
  uint16_t* D1W  = (uint16_t*)(ws + D1W_OFF);
  uint16_t* D2W  = (uint16_t*)(ws + D2W_OFF);
  float*    GRIDB= (float*)(ws + GRID_OFF);
  uint16_t* EGOT = (uint16_t*)(ws + EGOT_OFF);
  uint16_t* FEAT = (uint16_t*)(ws + FEAT_OFF);
  float*    QBUF = (float*)(ws + QBUF_OFF);
  uint16_t* OBUF = (uint16_t*)(ws + OBUF_OFF);
  uint16_t* D1B  = (uint16_t*)(ws + D1_OFF);
  float*    D2B  = (float*)(ws + D2_OFF);
  uint16_t* WC   = (uint16_t*)(ws + WC_OFF);
  float*    BE   = (float*)(ws + BE_OFF);
  uint16_t* ENCWB= (uint16_t*)(ws + ENCW_OFF);
  float*    TMAT = (float*)(ws + TMAT_OFF);
  float*    ST1  = (float*)(ws + ST1_OFF);
  float*    ST2  = (float*)(ws + ST2_OFF);
  float*    outF = (float*)d_out;

  // zero: scatter grid, Xp (borders), Y1p (borders), BN stats
  (void)hipMemsetAsync(ws + GRID_OFF, 0, 6422528, stream);
  (void)hipMemsetAsync(ws + XP_OFF,   0, 71303168, stream);
  (void)hipMemsetAsync(ws + Y1P_OFF,  0, 33554432, stream);
  (void)hipMemsetAsync(ws + ST1_OFF,  0, 4096, stream);
  (void)hipMemsetAsync(ws + ST2_OFF,  0, 4096, stream);

  // constants / weight packs (independent of activations)
  k_tmat<<<1,32,0,stream>>>(TMAT);
  k_lstm_prep<<<1,256,0,stream>>>(Wih,Whh,bih,bhh,sW,sb,encW, WC,BE,ENCWB);
  k_packw<<<dim3(512,17),64,0,stream>>>(conv1W, WP1, 512, 1088);
  k_packw<<<dim3(512,8), 64,0,stream>>>(conv2W, WP2, 512, 512);
  k_f2b<<<256,256,0,stream>>>(kWf, WKV,            1024*512);
  k_f2b<<<256,256,0,stream>>>(vWf, WKV + 1024*512, 1024*512);
  k_f2b<<<256,256,0,stream>>>(qWf, QW,  1024*576);
  k_f2b<<<256,256,0,stream>>>(aoW, AOW, 512*1024);
  k_f2b<<<32, 256,0,stream>>>(clsWf, CLSW, 25*1088);
  k_f2b<<<128,256,0,stream>>>(d1Wf, D1W, 256*1088);
  k_f2b<<<64, 256,0,stream>>>(d2Wf, D2W, 400*256);

  // encoders + scatter
  k_lstm<<<132,256,0,stream>>>(ego_seq, ag_seq, ego_len, ag_len, grid_pos,
                               WC, BE, ENCWB, encB, GRIDB, EGOT, FEAT);
  // conv input pack
  k_packx<<<dim3(128,34),256,0,stream>>>(cnn, GRIDB, XP);
  // conv1 -> BN1 -> relu (in place, padded)
  k_conv<0><<<dim3(4,196),256,0,stream>>>(XP, WP1, Y1P);
  k_bnstats<1><<<98,256,0,stream>>>(Y1P, ST1, 25088);
  k_bnapply<1><<<3136,256,0,stream>>>(Y1P, ST1, bn1g, bn1b, 25088, 1.f/25088.f, nullptr, nullptr);
  // conv2 -> BN2 -> relu (+ center pixel -> egoT/feat)
  k_conv<1><<<dim3(4,49),256,0,stream>>>(Y1P, WP2, Y2);
  k_bnstats<0><<<25,256,0,stream>>>(Y2, ST2, 6272);
  k_bnapply<0><<<784,256,0,stream>>>(Y2, ST2, bn2g, bn2b, 6272, 1.f/6272.f, EGOT, FEAT);
  // k,v 1x1 convs
  k_conv<2><<<dim3(16,49),256,0,stream>>>(Y2, WKV, KV);
  // q = egoT @ qW^T  (f32 out)
  k_sgemm<<<dim3(16,8),256,0,stream>>>(EGOT, 576, QW, 576, nullptr, QBUF, 1024, 1024, 576, 2);
  // attention
  k_attn<<<512,256,0,stream>>>(QBUF, KV, OBUF);
  // attn_out -> feat[:,0:512]
  k_sgemm<<<dim3(8,8),256,0,stream>>>(OBUF, 1024, AOW, 1024, aoB, FEAT, 1088, 512, 1024, 0);
  // conf -> d_out[121600:]
  k_sgemm<<<dim3(1,8),256,0,stream>>>(FEAT, 1088, CLSW, 1088, clsB, outF + 121600, 25, 25, 1088, 2);
  // dec1 (relu) -> dec2 -> traj
  k_sgemm<<<dim3(4,8),256,0,stream>>>(FEAT, 1088, D1W, 1088, d1B, D1B, 256, 256, 1088, 1);
  k_sgemm<<<dim3(7,8),256,0,stream>>>(D1B, 256, D2W, 256, d2B, D2B, 400, 400, 256, 2);
  k_traj<<<13,256,0,stream>>>(D2B, TMAT, outF);

  (void)in_sizes; (void)n_in; (void)out_size; (void)ws_size;
}

// Round 3
// 974.461 us; speedup vs baseline: 1.0765x; 1.0765x over previous
//
#include <hip/hip_runtime.h>
#include <stdint.h>
#include <stddef.h>

#define DEVINL static __device__ __forceinline__

typedef __attribute__((ext_vector_type(8))) short  bfrag;   // 8x bf16 (bits)
typedef __attribute__((ext_vector_type(4))) float  facc;    // MFMA accumulator

DEVINL uint16_t f2b(float f){
  uint32_t u = __float_as_uint(f);
  return (uint16_t)((u + 0x7fffu + ((u >> 16) & 1u)) >> 16);   // RNE
}
DEVINL float b2f(uint16_t b){ return __uint_as_float(((uint32_t)b) << 16); }

DEVINL facc MFMA(bfrag a, bfrag b, facc c){
  return __builtin_amdgcn_mfma_f32_16x16x32_bf16(a, b, c, 0, 0, 0);
}

// async global->LDS, 16B per lane; LDS dest = wave-uniform base + lane*16
DEVINL void gload16(const void* g, void* l){
  __builtin_amdgcn_global_load_lds(
      (const __attribute__((address_space(1))) uint32_t*)g,
      (__attribute__((address_space(3))) uint32_t*)l, 16, 0, 0);
}

DEVINL float fast_tanh(float x){           // tanh = 2*sigmoid(2x)-1
  return 2.f/(1.f+__expf(-2.f*x)) - 1.f;
}

// ---------------- multi-buffer f32 -> bf16 convert (one launch) ----------------
struct F2BJobs {
  const float* s[7];
  uint16_t*    d[7];
  int          n[7];
};
__global__ void k_f2b_multi(F2BJobs jobs){
  int j = blockIdx.y;
  const float* s = jobs.s[j];
  uint16_t* d = jobs.d[j];
  int n = jobs.n[j];
  int i = blockIdx.x*256 + threadIdx.x;
  int st = gridDim.x*256;
  for(; i<n; i+=st) d[i] = f2b(s[i]);
}

// ---------------- LSTM weight prep + Legendre tmat ----------------
// Wc[256][96] bf16 : [0..63]=Whh row, [64..68]=Wih@state_fc_W (folded), [69..95]=0
// be[256] = bih+bhh+Wih@state_fc_b ; encWb[64][64] bf16 ; tm[8][19]
__global__ void k_lstm_prep(const float* __restrict__ Wih, const float* __restrict__ Whh,
                            const float* __restrict__ bih, const float* __restrict__ bhh,
                            const float* __restrict__ sW, const float* __restrict__ sb,
                            const float* __restrict__ encW,
                            uint16_t* __restrict__ Wc, float* __restrict__ be,
                            uint16_t* __restrict__ encWb, float* __restrict__ tm){
  int n = threadIdx.x;
  if(n < 19){
    float tv = (float)(n - 6) / 12.0f;
    float Pm = 1.0f, Pc = tv;
    tm[0*19+n] = Pm * sqrtf(0.5f);
    tm[1*19+n] = Pc * sqrtf(1.5f);
    for(int q=1; q<7; q++){
      float Pn = ((float)(2*q+1)*tv*Pc - (float)q*Pm) / (float)(q+1);
      Pm = Pc; Pc = Pn;
      tm[(q+1)*19+n] = Pc * sqrtf((float)(2*(q+1)+1) * 0.5f);
    }
  }
  for(int k=0;k<64;k++) Wc[n*96+k] = f2b(Whh[n*64+k]);
  for(int k5=0;k5<5;k5++){
    float s = 0.f;
    for(int j=0;j<64;j++) s += Wih[n*64+j]*sW[j*5+k5];
    Wc[n*96+64+k5] = f2b(s);
  }
  for(int k=69;k<96;k++) Wc[n*96+k] = 0;
  float s = 0.f;
  for(int j=0;j<64;j++) s += Wih[n*64+j]*sb[j];
  be[n] = s + bih[n] + bhh[n];
  if(n < 64){
    for(int k=0;k<64;k++) encWb[n*64+k] = f2b(encW[n*64+k]);
  }
}

// ---------------- LSTM: 32 sequences / block, MFMA gates ----------------
__global__ __launch_bounds__(256) void k_lstm(
    const float* __restrict__ ego_seq, const float* __restrict__ ag_seq,
    const int* __restrict__ ego_len, const int* __restrict__ ag_len,
    const int* __restrict__ grid_pos,
    const uint16_t* __restrict__ Wc, const float* __restrict__ be,
    const uint16_t* __restrict__ encWb, const float* __restrict__ encB,
    float* __restrict__ agrid, uint16_t* __restrict__ egoT, uint16_t* __restrict__ feat)
{
  __shared__ __align__(16) uint16_t A[32*96];   // [seq][k] : k<64 h, 64..68 x_t, 69..95 zero
  __shared__ float Xf[32*160];                  // raw seq f32 [32][32][5]
  __shared__ int   idxs[32];

  int t = threadIdx.x, w = t>>6, l = t&63;
  int blk = blockIdx.x;
  bool isEgo = blk < 4;
  int seq0 = isEgo ? blk*32 : (blk-4)*32;
  const float* seqp = (isEgo ? ego_seq : ag_seq) + (size_t)seq0*160;

  for(int i=t;i<32*160;i+=256) Xf[i] = seqp[i];
  if(t < 32){
    int L = isEgo ? ego_len[seq0+t] : ag_len[seq0+t];
    if(L < 1) L = 1;
    idxs[t] = L-1;
  }
  for(int i=t;i<32*96;i+=256) A[i] = 0;

  bfrag bf[4][3];
  float be4[4];
  for(int ct=0;ct<4;ct++){
    int n = (ct*4+w)*16 + (l&15);
    for(int ks=0;ks<3;ks++)
      bf[ct][ks] = *(const bfrag*)(Wc + n*96 + ks*32 + (l>>4)*8);
    be4[ct] = be[n];
  }
  float cst[8], hl[8];
  for(int i=0;i<8;i++){ cst[i]=0.f; hl[i]=0.f; }
  __syncthreads();
  int myidx[8];
  for(int rt=0;rt<2;rt++) for(int r=0;r<4;r++){
    int s = rt*16 + (l>>4)*4 + r;
    myidx[rt*4+r] = idxs[s];
  }

  for(int st=0; st<32; st++){
    if(t < 160){ int s=t/5, kk=t%5; A[s*96+64+kk] = f2b(Xf[s*160 + st*5 + kk]); }
    __syncthreads();
    facc acc[2][4];
    for(int rt=0;rt<2;rt++) for(int ct=0;ct<4;ct++) acc[rt][ct] = facc{0.f,0.f,0.f,0.f};
    #pragma unroll
    for(int ks=0;ks<3;ks++){
      bfrag aA[2];
      #pragma unroll
      for(int rt=0;rt<2;rt++)
        aA[rt] = *(const bfrag*)(A + (rt*16+(l&15))*96 + ks*32 + (l>>4)*8);
      #pragma unroll
      for(int rt=0;rt<2;rt++)
        #pragma unroll
        for(int ct=0;ct<4;ct++)
          acc[rt][ct] = MFMA(aA[rt], bf[ct][ks], acc[rt][ct]);
    }
    __syncthreads();   // all A reads done before h overwrite
    #pragma unroll
    for(int rt=0;rt<2;rt++) for(int r=0;r<4;r++){
      int cell = rt*4+r;
      int s = rt*16 + (l>>4)*4 + r;
      float gi = acc[rt][0][r] + be4[0];
      float gf = acc[rt][1][r] + be4[1];
      float gg = acc[rt][2][r] + be4[2];
      float go = acc[rt][3][r] + be4[3];
      float si = 1.f/(1.f+__expf(-gi));
      float sf = 1.f/(1.f+__expf(-gf));
      float so = 1.f/(1.f+__expf(-go));
      float tg = fast_tanh(gg);
      float c2 = sf*cst[cell] + si*tg;
      cst[cell] = c2;
      float hn = so*fast_tanh(c2);
      A[s*96 + w*16 + (l&15)] = f2b(hn);
      if(st == myidx[cell]) hl[cell] = hn;
    }
  }
  __syncthreads();
  for(int rt=0;rt<2;rt++) for(int r=0;r<4;r++){
    int s = rt*16 + (l>>4)*4 + r;
    A[s*96 + w*16 + (l&15)] = f2b(hl[rt*4+r]);
  }
  __syncthreads();
  bfrag eb[2];
  for(int ks=0;ks<2;ks++)
    eb[ks] = *(const bfrag*)(encWb + (w*16+(l&15))*64 + ks*32 + (l>>4)*8);
  facc ea[2]; ea[0] = facc{0.f,0.f,0.f,0.f}; ea[1] = facc{0.f,0.f,0.f,0.f};
  for(int ks=0;ks<2;ks++){
    for(int rt=0;rt<2;rt++){
      bfrag aA = *(const bfrag*)(A + (rt*16+(l&15))*96 + ks*32 + (l>>4)*8);
      ea[rt] = MFMA(aA, eb[ks], ea[rt]);
    }
  }
  int n = w*16 + (l&15);
  float bn_ = encB[n];
  for(int rt=0;rt<2;rt++) for(int r=0;r<4;r++){
    int s = rt*16 + (l>>4)*4 + r;
    float v = ea[rt][r] + bn_;
    int gs = seq0 + s;
    if(isEgo){
      egoT[(size_t)gs*576 + 512 + n] = f2b(v);
      feat[(size_t)gs*1088 + 1024 + n] = f2b(v);
    } else {
      int py = grid_pos[gs*2+0], px = grid_pos[gs*2+1];
      atomicAdd(&agrid[((size_t)(gs>>5)*196 + py*14 + px)*64 + n], v);
    }
  }
}

// ---------------- pack conv1 input: NCHW f32 (+grid NHWC f32) -> padded NHWC bf16 ----------------
__global__ void k_packx(const float* __restrict__ cnn, const float* __restrict__ agrid,
                        uint16_t* __restrict__ Xp)
{
  __shared__ float tile[32*200];
  int b = blockIdx.x, ch = blockIdx.y, t = threadIdx.x;
  if(ch < 32){
    int c0 = ch*32;
    for(int i=t;i<32*196;i+=256){
      int ci = i/196, s = i%196;
      tile[ci*200+s] = cnn[((size_t)b*1024 + c0+ci)*196 + s];
    }
    __syncthreads();
    for(int i=t;i<32*196;i+=256){
      int s = i>>5, ci = i&31;
      int y = s/14, x = s%14;
      Xp[(((size_t)b*16 + y+1)*16 + x+1)*1088 + c0 + ci] = f2b(tile[ci*200+s]);
    }
  } else {
    int j0 = (ch-32)*32;
    for(int i=t;i<32*196;i+=256){
      int s = i>>5, ji = i&31;
      int y = s/14, x = s%14;
      Xp[(((size_t)b*16 + y+1)*16 + x+1)*1088 + 1024 + j0 + ji] =
          f2b(agrid[((size_t)b*196 + s)*64 + j0 + ji]);
    }
  }
}

// ---------------- pack conv weights OIHW f32 -> [dydx][O][C] bf16 (B^T layout) ----------------
__global__ void k_packw(const float* __restrict__ W, uint16_t* __restrict__ Wp, int O, int C)
{
  int o = blockIdx.x;
  int c = blockIdx.y*64 + threadIdx.x;
  const float* src = W + ((size_t)o*C + c)*9;
  float v[9];
  #pragma unroll
  for(int d=0;d<9;d++) v[d] = src[d];
  #pragma unroll
  for(int d=0;d<9;d++)
    Wp[((size_t)d*O + o)*C + c] = f2b(v[d]);
}

// ---------------- implicit-GEMM conv (m97-style 128x128, BK=64) ----------------
// MODE 0: conv1  (A=Xp padded NHWC, C=1088, out padded Y1p)   grid 784
// MODE 1: conv2  (A=Y1p padded, C=512, stride 2, out [6272][512]) grid 196
// MODE 2: kv 1x1 (A=Y2 [6272][512], out [6272][2048])         grid 784
// K-loop: register-held base pointers, constant-stride increments (no div/mod,
// no per-iter LDS reads). Block index XCD-chunk-swizzled (m204 bijective),
// n-major so each XCD keeps one B panel L2-resident.
template<int MODE>
__global__ __launch_bounds__(256) void k_conv(
    const uint16_t* __restrict__ Ain, const uint16_t* __restrict__ Wb,
    uint16_t* __restrict__ Out)
{
  constexpr int CB   = (MODE==0) ? 1088 : 512;
  constexpr int NB   = (MODE==2) ? 2048 : 512;
  constexpr int NDY  = (MODE==2) ? 1 : 9;
  constexpr int NCC  = (MODE==0) ? 17 : 8;
  constexpr int MT   = (MODE==0) ? 196 : 49;              // m-tiles
  constexpr int NT   = NB/128;                            // n-tiles
  constexpr int NWG  = MT*NT;
  constexpr int Q8   = NWG/8, R8 = NWG%8;
  static_assert(NCC*64 == CB, "cc loop must advance exactly one dx step");

  __shared__ __align__(16) uint16_t As[128*64];
  __shared__ __align__(16) uint16_t Bs[128*64];
  __shared__ int outOff[128];

  int t = threadIdx.x, w = t>>6, l = t&63;

  // bijective XCD-chunk swizzle (m204)
  int xcd = blockIdx.x & 7, pos = blockIdx.x >> 3;
  int wgid = (xcd < R8 ? xcd*(Q8+1) : R8*(Q8+1) + (xcd-R8)*Q8) + pos;
  int n0 = (wgid / MT) * 128;
  int m0 = (wgid % MT) * 128;

  if(t < 128){
    int m = m0 + t, oo;
    if(MODE==0){
      int b = m/196, s = m%196, y = s/14, x = s%14;
      oo = ((b*16 + y+1)*16 + (x+1))*512;
    } else if(MODE==1){
      oo = m*512;
    } else {
      oo = m*2048;
    }
    outOff[t] = oo;
  }

  // per-lane staging pointers: 4 A rows + 4 B rows, advanced by constant strides
  const uint16_t* aP[4];
  const uint16_t* bP[4];
  #pragma unroll
  for(int p=0;p<4;p++){
    int r = w*32 + p*8 + (l>>3);
    int m = m0 + r, ro;
    if(MODE==0){
      int b = m/196, s = m%196, y = s/14, x = s%14;
      ro = ((b*16 + y)*16 + x)*1088;
    } else if(MODE==1){
      int b = m/49, s = m%49, y = s/7, x = s%7;
      ro = ((b*16 + 2*y)*16 + 2*x)*512;
    } else {
      ro = m*512;
    }
    aP[p] = Ain + ro + (l&7)*8;
    bP[p] = Wb + (size_t)(n0 + r)*CB + (l&7)*8;
  }
  __syncthreads();

  facc acc[4][4];
  #pragma unroll
  for(int i=0;i<4;i++)
    #pragma unroll
    for(int j=0;j<4;j++) acc[i][j] = facc{0.f,0.f,0.f,0.f};
  int wm = w>>1, wn = w&1;
  char* asDst = (char*)As + w*4096;
  char* bsDst = (char*)Bs + w*4096;

  for(int d=0; d<NDY; d++){
    for(int cc=0; cc<NCC; cc++){
      #pragma unroll
      for(int p=0;p<4;p++){ gload16(aP[p], asDst + p*1024); aP[p] += 64; }
      #pragma unroll
      for(int p=0;p<4;p++){ gload16(bP[p], bsDst + p*1024); bP[p] += 64; }
      __syncthreads();
      #pragma unroll
      for(int ks=0;ks<2;ks++){
        bfrag a[4], b[4];
        #pragma unroll
        for(int i=0;i<4;i++)
          a[i] = *(const bfrag*)(As + (wm*64 + i*16 + (l&15))*64 + ks*32 + (l>>4)*8);
        #pragma unroll
        for(int j=0;j<4;j++)
          b[j] = *(const bfrag*)(Bs + (wn*64 + j*16 + (l&15))*64 + ks*32 + (l>>4)*8);
        #pragma unroll
        for(int i=0;i<4;i++)
          #pragma unroll
          for(int j=0;j<4;j++)
            acc[i][j] = MFMA(a[i], b[j], acc[i][j]);
      }
      __syncthreads();
    }
    if(MODE != 2){
      // after cc loop pointers advanced exactly CB (one dx step)
      int extraA = ((d%3)==2) ? 13*CB : 0;   // row wrap: next dy
      #pragma unroll
      for(int p=0;p<4;p++){ aP[p] += extraA; bP[p] += (NB-1)*CB; }
    }
  }

  #pragma unroll
  for(int i=0;i<4;i++)
    #pragma unroll
    for(int j=0;j<4;j++){
      int n = n0 + wn*64 + j*16 + (l&15);
      #pragma unroll
      for(int r=0;r<4;r++){
        int mr = wm*64 + i*16 + (l>>4)*4 + r;
        Out[(size_t)outOff[mr] + n] = f2b(acc[i][j][r]);
      }
    }
}

// ---------------- BN batch stats (sum/sumsq per channel, 512 ch, atomics) ----------------
template<int PAD>
__global__ void k_bnstats(const uint16_t* __restrict__ Y, float* __restrict__ stats, int M)
{
  int t = threadIdx.x;
  int m0 = blockIdx.x*256;
  float s0=0,s1=0,q0=0,q1=0;
  for(int i=0;i<256;i++){
    int m = m0+i; if(m>=M) break;
    size_t off;
    if(PAD){ int b=m/196, s=m%196, y=s/14, x=s%14; off = (((size_t)b*16+y+1)*16 + x+1)*512; }
    else off = (size_t)m*512;
    uint32_t u = *(const uint32_t*)(Y + off + 2*t);
    float a = b2f((uint16_t)u), c = b2f((uint16_t)(u>>16));
    s0+=a; q0+=a*a; s1+=c; q1+=c*c;
  }
  atomicAdd(&stats[4*t+0], s0);
  atomicAdd(&stats[4*t+1], q0);
  atomicAdd(&stats[4*t+2], s1);
  atomicAdd(&stats[4*t+3], q1);
}

// ---------------- BN apply + ReLU in-place; conv2 variant extracts center into egoT/feat ----------------
template<int PAD>
__global__ void k_bnapply(uint16_t* __restrict__ Y, const float* __restrict__ stats,
                          const float* __restrict__ gg, const float* __restrict__ bb,
                          int M, float invM,
                          uint16_t* __restrict__ egoT, uint16_t* __restrict__ feat)
{
  int t = threadIdx.x;
  int m0 = blockIdx.x*8;
  float mu0 = stats[4*t+0]*invM, mu1 = stats[4*t+2]*invM;
  float v0 = stats[4*t+1]*invM - mu0*mu0, v1 = stats[4*t+3]*invM - mu1*mu1;
  float sc0 = gg[2*t]  *rsqrtf(v0+1e-5f), sc1 = gg[2*t+1]*rsqrtf(v1+1e-5f);
  float sh0 = bb[2*t]   - mu0*sc0,        sh1 = bb[2*t+1] - mu1*sc1;
  for(int i=0;i<8;i++){
    int m = m0+i; if(m>=M) break;
    size_t off;
    if(PAD){ int b=m/196, s=m%196, y=s/14, x=s%14; off = (((size_t)b*16+y+1)*16 + x+1)*512; }
    else off = (size_t)m*512;
    uint32_t u = *(const uint32_t*)(Y + off + 2*t);
    float a = fmaxf(b2f((uint16_t)u)*sc0 + sh0, 0.f);
    float c = fmaxf(b2f((uint16_t)(u>>16))*sc1 + sh1, 0.f);
    uint32_t pu = (uint32_t)f2b(a) | ((uint32_t)f2b(c)<<16);
    *(uint32_t*)(Y + off + 2*t) = pu;
    if(!PAD && (m%49)==24){
      int b = m/49;
      *(uint32_t*)(egoT + (size_t)b*576 + 2*t) = pu;
      *(uint32_t*)(feat + (size_t)b*1088 + 512 + 2*t) = pu;
    }
  }
}

// ---------------- small-M GEMM (M=128), no LDS ----------------
// flags: 1 = relu, 2 = f32 output (else bf16)
__global__ __launch_bounds__(256) void k_sgemm(
    const uint16_t* __restrict__ A, int lda,
    const uint16_t* __restrict__ B, int ldb,
    const float* __restrict__ bias,
    void* __restrict__ C, int ldc,
    int N, int K, int flags)
{
  int t = threadIdx.x, w = t>>6, l = t&63;
  int nt = blockIdx.x*4 + w;
  int n  = nt*16 + (l&15);
  int m0 = blockIdx.y*16;
  bool nv = n < N;
  facc acc = facc{0.f,0.f,0.f,0.f};
  for(int k=0;k<K;k+=32){
    bfrag af = *(const bfrag*)(A + (size_t)(m0+(l&15))*lda + k + (l>>4)*8);
    bfrag bf_ = {0,0,0,0,0,0,0,0};
    if(nv) bf_ = *(const bfrag*)(B + (size_t)n*ldb + k + (l>>4)*8);
    acc = MFMA(af, bf_, acc);
  }
  if(nv){
    float bv = bias ? bias[n] : 0.f;
    #pragma unroll
    for(int r=0;r<4;r++){
      int m = m0 + (l>>4)*4 + r;
      float v = acc[r] + bv;
      if(flags & 1) v = fmaxf(v, 0.f);
      if(flags & 2) ((float*)C)[(size_t)m*ldc + n] = v;
      else ((uint16_t*)C)[(size_t)m*ldc + n] = f2b(v);
    }
  }
}

// ---------------- attention: one wave per (b,h); ring handled analytically ----------------
__global__ __launch_bounds__(256) void k_attn(
    const float* __restrict__ q, const uint16_t* __restrict__ kv,
    uint16_t* __restrict__ o)
{
  int t = threadIdx.x, w = t>>6, l = t&63;
  int idx = blockIdx.x*4 + w;          // b*16+h
  int b = idx>>4, h = idx&15;
  float qf = q[(size_t)b*1024 + h*64 + l];
  const uint16_t* kp = kv + (size_t)b*49*2048 + h*64 + l;
  float eo = 0.f;
  for(int g=0; g<49; g++){
    float p = qf * b2f(kp[(size_t)g*2048]);
    for(int s=32;s>0;s>>=1) p += __shfl_xor(p, s);
    if(l == g) eo = p;
  }
  float e = (l<49) ? eo*(1.f/32.f) : -1e30f;
  float mx = e;
  for(int s=32;s>0;s>>=1) mx = fmaxf(mx, __shfl_xor(mx, s));
  mx = fmaxf(mx, 0.f);                          // 32 ring slots have energy 0
  float p = (l<49) ? __expf(e-mx) : 0.f;
  float den = p;
  for(int s=32;s>0;s>>=1) den += __shfl_xor(den, s);
  den += 32.f*__expf(-mx);
  const uint16_t* vp = kv + (size_t)b*49*2048 + 1024 + h*64 + l;
  float accv = 0.f;
  for(int g=0; g<49; g++){
    float pg = __shfl(p, g);
    accv += pg * b2f(vp[(size_t)g*2048]);
  }
  o[(size_t)b*1024 + h*64 + l] = f2b(accv/den);
}

// ---------------- trajectory: d2[b][25][16] @ tmat -> out [b][25][19][2] ----------------
__global__ void k_traj(const float* __restrict__ d2, const float* __restrict__ tm,
                       float* __restrict__ out)
{
  int i = blockIdx.x*256 + threadIdx.x;
  if(i >= 3200) return;
  const float* dp = d2 + (size_t)i*16;
  float cx[8], cy[8];
  #pragma unroll
  for(int j=0;j<8;j++){ cx[j]=dp[j]; cy[j]=dp[8+j]; }
  float* op = out + (size_t)i*38;
  for(int tt=0;tt<19;tt++){
    float x=0.f, y=0.f;
    #pragma unroll
    for(int j=0;j<8;j++){ float tv = tm[j*19+tt]; x += cx[j]*tv; y += cy[j]*tv; }
    op[tt*2+0]=x; op[tt*2+1]=y;
  }
}

// ======================= host =======================
extern "C" void kernel_launch(void* const* d_in, const int* in_sizes, int n_in,
                              void* d_out, int out_size, void* d_ws, size_t ws_size,
                              hipStream_t stream)
{
  const float* cnn      = (const float*)d_in[0];
  const float* ego_seq  = (const float*)d_in[1];
  const float* ag_seq   = (const float*)d_in[2];
  const int*   ego_len  = (const int*)d_in[3];
  const int*   ag_len   = (const int*)d_in[4];
  const int*   grid_pos = (const int*)d_in[5];
  const float* sW  = (const float*)d_in[6];
  const float* sb  = (const float*)d_in[7];
  const float* Wih = (const float*)d_in[8];
  const float* Whh = (const float*)d_in[9];
  const float* bih = (const float*)d_in[10];
  const float* bhh = (const float*)d_in[11];
  const float* encW = (const float*)d_in[12];
  const float* encB = (const float*)d_in[13];
  const float* conv1W = (const float*)d_in[14];
  const float* bn1g = (const float*)d_in[15];
  const float* bn1b = (const float*)d_in[16];
  const float* conv2W = (const float*)d_in[17];
  const float* bn2g = (const float*)d_in[18];
  const float* bn2b = (const float*)d_in[19];
  const float* qWf  = (const float*)d_in[20];
  const float* kWf  = (const float*)d_in[21];
  const float* vWf  = (const float*)d_in[22];
  const float* aoW  = (const float*)d_in[23];
  const float* aoB  = (const float*)d_in[24];
  const float* clsWf = (const float*)d_in[25];
  const float* clsB  = (const float*)d_in[26];
  const float* d1Wf  = (const float*)d_in[27];
  const float* d1B   = (const float*)d_in[28];
  const float* d2Wf  = (const float*)d_in[29];
  const float* d2B   = (const float*)d_in[30];

  char* ws = (char*)d_ws;
  const size_t XP_OFF   = 0;                 // 71,303,168
  const size_t KV_OFF   = 0;                 // alias: after Xp dead
  const size_t Y2_OFF   = 29360128;          // alias inside Xp region
  const size_t Y1P_OFF  = 71303168;          // 33,554,432
  const size_t WP1_OFF  = 104857600;
  const size_t WP2_OFF  = 114884608;
  const size_t WKV_OFF  = 119603200;
  const size_t QW_OFF   = 121700352;
  const size_t AOW_OFF  = 122880000;
  const size_t CLSW_OFF = 123928576;
  const size_t D1W_OFF  = 123982976;
  const size_t D2W_OFF  = 124540032;
  const size_t GRID_OFF = 124744832;
  const size_t EGOT_OFF = 131167360;
  const size_t FEAT_OFF = 131314816;
  const size_t QBUF_OFF = 131593344;
  const size_t OBUF_OFF = 132117632;
  const size_t D1_OFF   = 132379776;
  const size_t D2_OFF   = 132445312;
  const size_t WC_OFF   = 132650112;
  const size_t BE_OFF   = 132699264;
  const size_t ENCW_OFF = 132700288;
  const size_t TMAT_OFF = 132708480;
  const size_t ST1_OFF  = 132709120;
  const size_t ST2_OFF  = 132713216;

  uint16_t* XP   = (uint16_t*)(ws + XP_OFF);
  uint16_t* KV   = (uint16_t*)(ws + KV_OFF);
  uint16_t* Y2   = (uint16_t*)(ws + Y2_OFF);
  uint16_t* Y1P  = (uint16_t*)(ws + Y1P_OFF);
  uint16_t* WP1  = (uint16_t*)(ws + WP1_OFF);
  uint16_t* WP2  = (uint16_t*)(ws + WP2_OFF);
  uint16_t* WKV  = (uint16_t*)(ws + WKV_OFF);
  uint16_t* QW   = (uint16_t*)(ws + QW_OFF);
  uint16_t* AOW  = (uint16_t*)(ws + AOW_OFF);
  uint16_t* CLSW = (uint16_t*)(ws + CLSW_OFF);
  uint16_t* D1W  = (uint16_t*)(ws + D1W_OFF);
  uint16_t* D2W  = (uint16_t*)(ws + D2W_OFF);
  float*    GRIDB= (float*)(ws + GRID_OFF);
  uint16_t* EGOT = (uint16_t*)(ws + EGOT_OFF);
  uint16_t* FEAT = (uint16_t*)(ws + FEAT_OFF);
  float*    QBUF = (float*)(ws + QBUF_OFF);
  uint16_t* OBUF = (uint16_t*)(ws + OBUF_OFF);
  uint16_t* D1B  = (uint16_t*)(ws + D1_OFF);
  float*    D2B  = (float*)(ws + D2_OFF);
  uint16_t* WC   = (uint16_t*)(ws + WC_OFF);
  float*    BE   = (float*)(ws + BE_OFF);
  uint16_t* ENCWB= (uint16_t*)(ws + ENCW_OFF);
  float*    TMAT = (float*)(ws + TMAT_OFF);
  float*    ST1  = (float*)(ws + ST1_OFF);
  float*    ST2  = (float*)(ws + ST2_OFF);
  float*    outF = (float*)d_out;

  (void)hipMemsetAsync(ws + GRID_OFF, 0, 6422528, stream);
  (void)hipMemsetAsync(ws + XP_OFF,   0, 71303168, stream);
  (void)hipMemsetAsync(ws + Y1P_OFF,  0, 33554432, stream);
  (void)hipMemsetAsync(ws + ST1_OFF,  0, 4096, stream);
  (void)hipMemsetAsync(ws + ST2_OFF,  0, 4096, stream);

  // constants / weight packs
  k_lstm_prep<<<1,256,0,stream>>>(Wih,Whh,bih,bhh,sW,sb,encW, WC,BE,ENCWB, TMAT);
  k_packw<<<dim3(512,17),64,0,stream>>>(conv1W, WP1, 512, 1088);
  k_packw<<<dim3(512,8), 64,0,stream>>>(conv2W, WP2, 512, 512);
  {
    F2BJobs jb;
    jb.s[0]=kWf;  jb.d[0]=WKV;              jb.n[0]=1024*512;
    jb.s[1]=vWf;  jb.d[1]=WKV + 1024*512;   jb.n[1]=1024*512;
    jb.s[2]=qWf;  jb.d[2]=QW;               jb.n[2]=1024*576;
    jb.s[3]=aoW;  jb.d[3]=AOW;              jb.n[3]=512*1024;
    jb.s[4]=clsWf;jb.d[4]=CLSW;             jb.n[4]=25*1088;
    jb.s[5]=d1Wf; jb.d[5]=D1W;              jb.n[5]=256*1088;
    jb.s[6]=d2Wf; jb.d[6]=D2W;              jb.n[6]=400*256;
    k_f2b_multi<<<dim3(48,7),256,0,stream>>>(jb);
  }

  // encoders + scatter
  k_lstm<<<132,256,0,stream>>>(ego_seq, ag_seq, ego_len, ag_len, grid_pos,
                               WC, BE, ENCWB, encB, GRIDB, EGOT, FEAT);
  // conv input pack
  k_packx<<<dim3(128,34),256,0,stream>>>(cnn, GRIDB, XP);
  // conv1 -> BN1 -> relu (in place, padded)
  k_conv<0><<<784,256,0,stream>>>(XP, WP1, Y1P);
  k_bnstats<1><<<98,256,0,stream>>>(Y1P, ST1, 25088);
  k_bnapply<1><<<3136,256,0,stream>>>(Y1P, ST1, bn1g, bn1b, 25088, 1.f/25088.f, nullptr, nullptr);
  // conv2 -> BN2 -> relu (+ center pixel -> egoT/feat)
  k_conv<1><<<196,256,0,stream>>>(Y1P, WP2, Y2);
  k_bnstats<0><<<25,256,0,stream>>>(Y2, ST2, 6272);
  k_bnapply<0><<<784,256,0,stream>>>(Y2, ST2, bn2g, bn2b, 6272, 1.f/6272.f, EGOT, FEAT);
  // k,v 1x1 convs
  k_conv<2><<<784,256,0,stream>>>(Y2, WKV, KV);
  // q = egoT @ qW^T  (f32 out)
  k_sgemm<<<dim3(16,8),256,0,stream>>>(EGOT, 576, QW, 576, nullptr, QBUF, 1024, 1024, 576, 2);
  // attention
  k_attn<<<512,256,0,stream>>>(QBUF, KV, OBUF);
  // attn_out -> feat[:,0:512]
  k_sgemm<<<dim3(8,8),256,0,stream>>>(OBUF, 1024, AOW, 1024, aoB, FEAT, 1088, 512, 1024, 0);
  // conf -> d_out[121600:]
  k_sgemm<<<dim3(1,8),256,0,stream>>>(FEAT, 1088, CLSW, 1088, clsB, outF + 121600, 25, 25, 1088, 2);
  // dec1 (relu) -> dec2 -> traj
  k_sgemm<<<dim3(4,8),256,0,stream>>>(FEAT, 1088, D1W, 1088, d1B, D1B, 256, 256, 1088, 1);
  k_sgemm<<<dim3(7,8),256,0,stream>>>(D1B, 256, D2W, 256, d2B, D2B, 400, 400, 256, 2);
  k_traj<<<13,256,0,stream>>>(D2B, TMAT, outF);

  (void)in_sizes; (void)n_in; (void)out_size; (void)ws_size;
}

// Round 4
// 794.431 us; speedup vs baseline: 1.3204x; 1.2266x over previous
//
#include <hip/hip_runtime.h>
#include <stdint.h>
#include <stddef.h>

#define DEVINL static __device__ __forceinline__

typedef __attribute__((ext_vector_type(8))) short  bfrag;   // 8x bf16 (bits)
typedef __attribute__((ext_vector_type(4))) float  facc;    // MFMA accumulator

DEVINL uint16_t f2b(float f){
  uint32_t u = __float_as_uint(f);
  return (uint16_t)((u + 0x7fffu + ((u >> 16) & 1u)) >> 16);   // RNE
}
DEVINL float b2f(uint16_t b){ return __uint_as_float(((uint32_t)b) << 16); }

DEVINL facc MFMA(bfrag a, bfrag b, facc c){
  return __builtin_amdgcn_mfma_f32_16x16x32_bf16(a, b, c, 0, 0, 0);
}

// async global->LDS, 16B per lane; LDS dest = wave-uniform base + lane*16
DEVINL void gload16(const void* g, void* l){
  __builtin_amdgcn_global_load_lds(
      (const __attribute__((address_space(1))) uint32_t*)g,
      (__attribute__((address_space(3))) uint32_t*)l, 16, 0, 0);
}

DEVINL float fast_tanh(float x){           // tanh = 2*sigmoid(2x)-1
  return 2.f/(1.f+__expf(-2.f*x)) - 1.f;
}

// ---------------- multi-buffer f32 -> bf16 convert (one launch) ----------------
struct F2BJobs {
  const float* s[7];
  uint16_t*    d[7];
  int          n[7];
};
__global__ void k_f2b_multi(F2BJobs jobs){
  int j = blockIdx.y;
  const float* s = jobs.s[j];
  uint16_t* d = jobs.d[j];
  int n = jobs.n[j];
  int i = blockIdx.x*256 + threadIdx.x;
  int st = gridDim.x*256;
  for(; i<n; i+=st) d[i] = f2b(s[i]);
}

// ---------------- LSTM weight prep + Legendre tmat ----------------
__global__ void k_lstm_prep(const float* __restrict__ Wih, const float* __restrict__ Whh,
                            const float* __restrict__ bih, const float* __restrict__ bhh,
                            const float* __restrict__ sW, const float* __restrict__ sb,
                            const float* __restrict__ encW,
                            uint16_t* __restrict__ Wc, float* __restrict__ be,
                            uint16_t* __restrict__ encWb, float* __restrict__ tm){
  int n = threadIdx.x;
  if(n < 19){
    float tv = (float)(n - 6) / 12.0f;
    float Pm = 1.0f, Pc = tv;
    tm[0*19+n] = Pm * sqrtf(0.5f);
    tm[1*19+n] = Pc * sqrtf(1.5f);
    for(int q=1; q<7; q++){
      float Pn = ((float)(2*q+1)*tv*Pc - (float)q*Pm) / (float)(q+1);
      Pm = Pc; Pc = Pn;
      tm[(q+1)*19+n] = Pc * sqrtf((float)(2*(q+1)+1) * 0.5f);
    }
  }
  for(int k=0;k<64;k++) Wc[n*96+k] = f2b(Whh[n*64+k]);
  for(int k5=0;k5<5;k5++){
    float s = 0.f;
    for(int j=0;j<64;j++) s += Wih[n*64+j]*sW[j*5+k5];
    Wc[n*96+64+k5] = f2b(s);
  }
  for(int k=69;k<96;k++) Wc[n*96+k] = 0;
  float s = 0.f;
  for(int j=0;j<64;j++) s += Wih[n*64+j]*sb[j];
  be[n] = s + bih[n] + bhh[n];
  if(n < 64){
    for(int k=0;k<64;k++) encWb[n*64+k] = f2b(encW[n*64+k]);
  }
}

// ---------------- LSTM: 32 sequences / block, MFMA gates ----------------
__global__ __launch_bounds__(256) void k_lstm(
    const float* __restrict__ ego_seq, const float* __restrict__ ag_seq,
    const int* __restrict__ ego_len, const int* __restrict__ ag_len,
    const int* __restrict__ grid_pos,
    const uint16_t* __restrict__ Wc, const float* __restrict__ be,
    const uint16_t* __restrict__ encWb, const float* __restrict__ encB,
    float* __restrict__ agrid, uint16_t* __restrict__ egoT, uint16_t* __restrict__ feat)
{
  __shared__ __align__(16) uint16_t A[32*96];   // [seq][k] : k<64 h, 64..68 x_t, 69..95 zero
  __shared__ float Xf[32*160];                  // raw seq f32 [32][32][5]
  __shared__ int   idxs[32];

  int t = threadIdx.x, w = t>>6, l = t&63;
  int blk = blockIdx.x;
  bool isEgo = blk < 4;
  int seq0 = isEgo ? blk*32 : (blk-4)*32;
  const float* seqp = (isEgo ? ego_seq : ag_seq) + (size_t)seq0*160;

  for(int i=t;i<32*160;i+=256) Xf[i] = seqp[i];
  if(t < 32){
    int L = isEgo ? ego_len[seq0+t] : ag_len[seq0+t];
    if(L < 1) L = 1;
    idxs[t] = L-1;
  }
  for(int i=t;i<32*96;i+=256) A[i] = 0;

  bfrag bf[4][3];
  float be4[4];
  for(int ct=0;ct<4;ct++){
    int n = (ct*4+w)*16 + (l&15);
    for(int ks=0;ks<3;ks++)
      bf[ct][ks] = *(const bfrag*)(Wc + n*96 + ks*32 + (l>>4)*8);
    be4[ct] = be[n];
  }
  float cst[8], hl[8];
  for(int i=0;i<8;i++){ cst[i]=0.f; hl[i]=0.f; }
  __syncthreads();
  int myidx[8];
  for(int rt=0;rt<2;rt++) for(int r=0;r<4;r++){
    int s = rt*16 + (l>>4)*4 + r;
    myidx[rt*4+r] = idxs[s];
  }

  for(int st=0; st<32; st++){
    if(t < 160){ int s=t/5, kk=t%5; A[s*96+64+kk] = f2b(Xf[s*160 + st*5 + kk]); }
    __syncthreads();
    facc acc[2][4];
    for(int rt=0;rt<2;rt++) for(int ct=0;ct<4;ct++) acc[rt][ct] = facc{0.f,0.f,0.f,0.f};
    #pragma unroll
    for(int ks=0;ks<3;ks++){
      bfrag aA[2];
      #pragma unroll
      for(int rt=0;rt<2;rt++)
        aA[rt] = *(const bfrag*)(A + (rt*16+(l&15))*96 + ks*32 + (l>>4)*8);
      #pragma unroll
      for(int rt=0;rt<2;rt++)
        #pragma unroll
        for(int ct=0;ct<4;ct++)
          acc[rt][ct] = MFMA(aA[rt], bf[ct][ks], acc[rt][ct]);
    }
    __syncthreads();   // all A reads done before h overwrite
    #pragma unroll
    for(int rt=0;rt<2;rt++) for(int r=0;r<4;r++){
      int cell = rt*4+r;
      int s = rt*16 + (l>>4)*4 + r;
      float gi = acc[rt][0][r] + be4[0];
      float gf = acc[rt][1][r] + be4[1];
      float gg = acc[rt][2][r] + be4[2];
      float go = acc[rt][3][r] + be4[3];
      float si = 1.f/(1.f+__expf(-gi));
      float sf = 1.f/(1.f+__expf(-gf));
      float so = 1.f/(1.f+__expf(-go));
      float tg = fast_tanh(gg);
      float c2 = sf*cst[cell] + si*tg;
      cst[cell] = c2;
      float hn = so*fast_tanh(c2);
      A[s*96 + w*16 + (l&15)] = f2b(hn);
      if(st == myidx[cell]) hl[cell] = hn;
    }
  }
  __syncthreads();
  for(int rt=0;rt<2;rt++) for(int r=0;r<4;r++){
    int s = rt*16 + (l>>4)*4 + r;
    A[s*96 + w*16 + (l&15)] = f2b(hl[rt*4+r]);
  }
  __syncthreads();
  bfrag eb[2];
  for(int ks=0;ks<2;ks++)
    eb[ks] = *(const bfrag*)(encWb + (w*16+(l&15))*64 + ks*32 + (l>>4)*8);
  facc ea[2]; ea[0] = facc{0.f,0.f,0.f,0.f}; ea[1] = facc{0.f,0.f,0.f,0.f};
  for(int ks=0;ks<2;ks++){
    for(int rt=0;rt<2;rt++){
      bfrag aA = *(const bfrag*)(A + (rt*16+(l&15))*96 + ks*32 + (l>>4)*8);
      ea[rt] = MFMA(aA, eb[ks], ea[rt]);
    }
  }
  int n = w*16 + (l&15);
  float bn_ = encB[n];
  for(int rt=0;rt<2;rt++) for(int r=0;r<4;r++){
    int s = rt*16 + (l>>4)*4 + r;
    float v = ea[rt][r] + bn_;
    int gs = seq0 + s;
    if(isEgo){
      egoT[(size_t)gs*576 + 512 + n] = f2b(v);
      feat[(size_t)gs*1088 + 1024 + n] = f2b(v);
    } else {
      int py = grid_pos[gs*2+0], px = grid_pos[gs*2+1];
      atomicAdd(&agrid[((size_t)(gs>>5)*196 + py*14 + px)*64 + n], v);
    }
  }
}

// ---------------- pack conv1 input: NCHW f32 (+grid NHWC f32) -> padded NHWC bf16 ----------------
__global__ void k_packx(const float* __restrict__ cnn, const float* __restrict__ agrid,
                        uint16_t* __restrict__ Xp)
{
  __shared__ float tile[32*200];
  int b = blockIdx.x, ch = blockIdx.y, t = threadIdx.x;
  if(ch < 32){
    int c0 = ch*32;
    for(int i=t;i<32*196;i+=256){
      int ci = i/196, s = i%196;
      tile[ci*200+s] = cnn[((size_t)b*1024 + c0+ci)*196 + s];
    }
    __syncthreads();
    for(int i=t;i<32*196;i+=256){
      int s = i>>5, ci = i&31;
      int y = s/14, x = s%14;
      Xp[(((size_t)b*16 + y+1)*16 + x+1)*1088 + c0 + ci] = f2b(tile[ci*200+s]);
    }
  } else {
    int j0 = (ch-32)*32;
    for(int i=t;i<32*196;i+=256){
      int s = i>>5, ji = i&31;
      int y = s/14, x = s%14;
      Xp[(((size_t)b*16 + y+1)*16 + x+1)*1088 + 1024 + j0 + ji] =
          f2b(agrid[((size_t)b*196 + s)*64 + j0 + ji]);
    }
  }
}

// ---------------- pack conv weights OIHW f32 -> [dydx][O][C] bf16 (B^T layout) ----------------
__global__ void k_packw(const float* __restrict__ W, uint16_t* __restrict__ Wp, int O, int C)
{
  int o = blockIdx.x;
  int c = blockIdx.y*64 + threadIdx.x;
  const float* src = W + ((size_t)o*C + c)*9;
  float v[9];
  #pragma unroll
  for(int d=0;d<9;d++) v[d] = src[d];
  #pragma unroll
  for(int d=0;d<9;d++)
    Wp[((size_t)d*O + o)*C + c] = f2b(v[d]);
}

// ---------------- implicit-GEMM conv (128x128, BK=64), cc-outer / tap-inner ----------------
// MODE 0: conv1  (A=Xp padded NHWC, C=1088, out padded Y1p)      grid 784
// MODE 1: conv2  (A=Y1p padded, C=512, stride 2, out [6272][512]) grid 196
// MODE 2: kv 1x1 (A=Y2 [6272][512], out [6272][2048])            grid 784
// Tap is the INNER loop so consecutive stages re-read (almost) the same A rows
// -> tap-to-tap reuse lands in L2 (per-XCD footprint ~1.3MB A + 2.5MB B < 4MB).
// BN partial stats (sum/sumsq per out-channel) folded into the epilogue.
template<int MODE>
__global__ __launch_bounds__(256) void k_conv(
    const uint16_t* __restrict__ Ain, const uint16_t* __restrict__ Wb,
    uint16_t* __restrict__ Out, float* __restrict__ stats)
{
  constexpr int CB   = (MODE==0) ? 1088 : 512;
  constexpr int NB   = (MODE==2) ? 2048 : 512;
  constexpr int NDY  = (MODE==2) ? 1 : 9;
  constexpr int NCC  = (MODE==0) ? 17 : 8;
  constexpr int MT   = (MODE==0) ? 196 : 49;              // m-tiles
  constexpr int NT   = NB/128;                            // n-tiles
  constexpr int NWG  = MT*NT;
  constexpr int Q8   = NWG/8, R8 = NWG%8;
  static_assert(NCC*64 == CB, "cc loop must advance exactly one dx step");

  __shared__ __align__(16) uint16_t As[128*64];
  __shared__ __align__(16) uint16_t Bs[128*64];
  __shared__ int outOff[128];

  int t = threadIdx.x, w = t>>6, l = t&63;

  // bijective XCD-chunk swizzle (m204)
  int xcd = blockIdx.x & 7, pos = blockIdx.x >> 3;
  int wgid = (xcd < R8 ? xcd*(Q8+1) : R8*(Q8+1) + (xcd-R8)*Q8) + pos;
  int n0 = (wgid / MT) * 128;
  int m0 = (wgid % MT) * 128;

  if(t < 128){
    int m = m0 + t, oo;
    if(MODE==0){
      int b = m/196, s = m%196, y = s/14, x = s%14;
      oo = ((b*16 + y+1)*16 + (x+1))*512;
    } else if(MODE==1){
      oo = m*512;
    } else {
      oo = m*2048;
    }
    outOff[t] = oo;
  }

  // per-lane staging pointers: 4 A rows + 4 B rows, constant-stride advanced
  const uint16_t* aP[4];
  const uint16_t* bP[4];
  #pragma unroll
  for(int p=0;p<4;p++){
    int r = w*32 + p*8 + (l>>3);
    int m = m0 + r, ro;
    if(MODE==0){
      int b = m/196, s = m%196, y = s/14, x = s%14;
      ro = ((b*16 + y)*16 + x)*1088;
    } else if(MODE==1){
      int b = m/49, s = m%49, y = s/7, x = s%7;
      ro = ((b*16 + 2*y)*16 + 2*x)*512;
    } else {
      ro = m*512;
    }
    aP[p] = Ain + ro + (l&7)*8;
    bP[p] = Wb + (size_t)(n0 + r)*CB + (l&7)*8;
  }
  __syncthreads();

  facc acc[4][4];
  #pragma unroll
  for(int i=0;i<4;i++)
    #pragma unroll
    for(int j=0;j<4;j++) acc[i][j] = facc{0.f,0.f,0.f,0.f};
  int wm = w>>1, wn = w&1;
  char* asDst = (char*)As + w*4096;
  char* bsDst = (char*)Bs + w*4096;

  for(int cc=0; cc<NCC; cc++){
    for(int d=0; d<NDY; d++){
      #pragma unroll
      for(int p=0;p<4;p++) gload16(aP[p], asDst + p*1024);
      #pragma unroll
      for(int p=0;p<4;p++) gload16(bP[p], bsDst + p*1024);
      if(MODE != 2){
        int stepA = ((d%3)==2) ? 14*CB : CB;      // tap walk: dx+1 or (dy+1, dx=0)
        #pragma unroll
        for(int p=0;p<4;p++){ aP[p] += stepA; bP[p] += NB*CB; }
      }
      __syncthreads();
      #pragma unroll
      for(int ks=0;ks<2;ks++){
        bfrag a[4], b[4];
        #pragma unroll
        for(int i=0;i<4;i++)
          a[i] = *(const bfrag*)(As + (wm*64 + i*16 + (l&15))*64 + ks*32 + (l>>4)*8);
        #pragma unroll
        for(int j=0;j<4;j++)
          b[j] = *(const bfrag*)(Bs + (wn*64 + j*16 + (l&15))*64 + ks*32 + (l>>4)*8);
        #pragma unroll
        for(int i=0;i<4;i++)
          #pragma unroll
          for(int j=0;j<4;j++)
            acc[i][j] = MFMA(a[i], b[j], acc[i][j]);
      }
      __syncthreads();
    }
    // next cc: A back to tap 0 (+64 ch), B back to tap 0 (+64 ch)
    int resetA = (MODE==2) ? 64 : 64 - 48*CB;
    int resetB = (MODE==2) ? 64 : 64 - 9*NB*CB;
    #pragma unroll
    for(int p=0;p<4;p++){ aP[p] += resetA; bP[p] += resetB; }
  }

  #pragma unroll
  for(int i=0;i<4;i++)
    #pragma unroll
    for(int j=0;j<4;j++){
      int n = n0 + wn*64 + j*16 + (l&15);
      #pragma unroll
      for(int r=0;r<4;r++){
        int mr = wm*64 + i*16 + (l>>4)*4 + r;
        Out[(size_t)outOff[mr] + n] = f2b(acc[i][j][r]);
      }
    }

  if(MODE != 2){
    // fold BN partial stats: per out-channel sum/sumsq over this block's 128 m
    float* sred = (float*)As;                 // [128 n][8 rowgrp][2] = 8 KB
    int rg = wm*4 + (l>>4);
    #pragma unroll
    for(int j=0;j<4;j++){
      float s=0.f, q=0.f;
      #pragma unroll
      for(int i=0;i<4;i++)
        #pragma unroll
        for(int r=0;r<4;r++){ float v = acc[i][j][r]; s += v; q += v*v; }
      int nl = wn*64 + j*16 + (l&15);
      sred[(nl*8 + rg)*2+0] = s;
      sred[(nl*8 + rg)*2+1] = q;
    }
    __syncthreads();
    if(t < 128){
      float s=0.f, q=0.f;
      #pragma unroll
      for(int rgi=0;rgi<8;rgi++){ s += sred[(t*8+rgi)*2]; q += sred[(t*8+rgi)*2+1]; }
      atomicAdd(&stats[n0+t], s);
      atomicAdd(&stats[512+n0+t], q);
    }
  }
}

// ---------------- BN apply + ReLU in-place; conv2 variant extracts center into egoT/feat ----------------
// stats layout: [0..511]=sum, [512..1023]=sumsq
template<int PAD>
__global__ void k_bnapply(uint16_t* __restrict__ Y, const float* __restrict__ stats,
                          const float* __restrict__ gg, const float* __restrict__ bb,
                          int M, float invM,
                          uint16_t* __restrict__ egoT, uint16_t* __restrict__ feat)
{
  int t = threadIdx.x;
  int m0 = blockIdx.x*8;
  float mu0 = stats[2*t]*invM,       mu1 = stats[2*t+1]*invM;
  float v0 = stats[512+2*t]*invM - mu0*mu0, v1 = stats[512+2*t+1]*invM - mu1*mu1;
  float sc0 = gg[2*t]  *rsqrtf(v0+1e-5f), sc1 = gg[2*t+1]*rsqrtf(v1+1e-5f);
  float sh0 = bb[2*t]   - mu0*sc0,        sh1 = bb[2*t+1] - mu1*sc1;
  for(int i=0;i<8;i++){
    int m = m0+i; if(m>=M) break;
    size_t off;
    if(PAD){ int b=m/196, s=m%196, y=s/14, x=s%14; off = (((size_t)b*16+y+1)*16 + x+1)*512; }
    else off = (size_t)m*512;
    uint32_t u = *(const uint32_t*)(Y + off + 2*t);
    float a = fmaxf(b2f((uint16_t)u)*sc0 + sh0, 0.f);
    float c = fmaxf(b2f((uint16_t)(u>>16))*sc1 + sh1, 0.f);
    uint32_t pu = (uint32_t)f2b(a) | ((uint32_t)f2b(c)<<16);
    *(uint32_t*)(Y + off + 2*t) = pu;
    if(!PAD && (m%49)==24){
      int b = m/49;
      *(uint32_t*)(egoT + (size_t)b*576 + 2*t) = pu;
      *(uint32_t*)(feat + (size_t)b*1088 + 512 + 2*t) = pu;
    }
  }
}

// ---------------- small-M GEMM (M=128), no LDS ----------------
// flags: 1 = relu, 2 = f32 output (else bf16)
__global__ __launch_bounds__(256) void k_sgemm(
    const uint16_t* __restrict__ A, int lda,
    const uint16_t* __restrict__ B, int ldb,
    const float* __restrict__ bias,
    void* __restrict__ C, int ldc,
    int N, int K, int flags)
{
  int t = threadIdx.x, w = t>>6, l = t&63;
  int nt = blockIdx.x*4 + w;
  int n  = nt*16 + (l&15);
  int m0 = blockIdx.y*16;
  bool nv = n < N;
  facc acc = facc{0.f,0.f,0.f,0.f};
  for(int k=0;k<K;k+=32){
    bfrag af = *(const bfrag*)(A + (size_t)(m0+(l&15))*lda + k + (l>>4)*8);
    bfrag bf_ = {0,0,0,0,0,0,0,0};
    if(nv) bf_ = *(const bfrag*)(B + (size_t)n*ldb + k + (l>>4)*8);
    acc = MFMA(af, bf_, acc);
  }
  if(nv){
    float bv = bias ? bias[n] : 0.f;
    #pragma unroll
    for(int r=0;r<4;r++){
      int m = m0 + (l>>4)*4 + r;
      float v = acc[r] + bv;
      if(flags & 1) v = fmaxf(v, 0.f);
      if(flags & 2) ((float*)C)[(size_t)m*ldc + n] = v;
      else ((uint16_t*)C)[(size_t)m*ldc + n] = f2b(v);
    }
  }
}

// ---------------- attention: one wave per (b,h); ring handled analytically ----------------
__global__ __launch_bounds__(256) void k_attn(
    const float* __restrict__ q, const uint16_t* __restrict__ kv,
    uint16_t* __restrict__ o)
{
  int t = threadIdx.x, w = t>>6, l = t&63;
  int idx = blockIdx.x*4 + w;          // b*16+h
  int b = idx>>4, h = idx&15;
  float qf = q[(size_t)b*1024 + h*64 + l];
  const uint16_t* kp = kv + (size_t)b*49*2048 + h*64 + l;
  float eo = 0.f;
  for(int g=0; g<49; g++){
    float p = qf * b2f(kp[(size_t)g*2048]);
    for(int s=32;s>0;s>>=1) p += __shfl_xor(p, s);
    if(l == g) eo = p;
  }
  float e = (l<49) ? eo*(1.f/32.f) : -1e30f;
  float mx = e;
  for(int s=32;s>0;s>>=1) mx = fmaxf(mx, __shfl_xor(mx, s));
  mx = fmaxf(mx, 0.f);                          // 32 ring slots have energy 0
  float p = (l<49) ? __expf(e-mx) : 0.f;
  float den = p;
  for(int s=32;s>0;s>>=1) den += __shfl_xor(den, s);
  den += 32.f*__expf(-mx);
  const uint16_t* vp = kv + (size_t)b*49*2048 + 1024 + h*64 + l;
  float accv = 0.f;
  for(int g=0; g<49; g++){
    float pg = __shfl(p, g);
    accv += pg * b2f(vp[(size_t)g*2048]);
  }
  o[(size_t)b*1024 + h*64 + l] = f2b(accv/den);
}

// ---------------- trajectory: d2[b][25][16] @ tmat -> out [b][25][19][2] ----------------
__global__ void k_traj(const float* __restrict__ d2, const float* __restrict__ tm,
                       float* __restrict__ out)
{
  int i = blockIdx.x*256 + threadIdx.x;
  if(i >= 3200) return;
  const float* dp = d2 + (size_t)i*16;
  float cx[8], cy[8];
  #pragma unroll
  for(int j=0;j<8;j++){ cx[j]=dp[j]; cy[j]=dp[8+j]; }
  float* op = out + (size_t)i*38;
  for(int tt=0;tt<19;tt++){
    float x=0.f, y=0.f;
    #pragma unroll
    for(int j=0;j<8;j++){ float tv = tm[j*19+tt]; x += cx[j]*tv; y += cy[j]*tv; }
    op[tt*2+0]=x; op[tt*2+1]=y;
  }
}

// ======================= host =======================
extern "C" void kernel_launch(void* const* d_in, const int* in_sizes, int n_in,
                              void* d_out, int out_size, void* d_ws, size_t ws_size,
                              hipStream_t stream)
{
  const float* cnn      = (const float*)d_in[0];
  const float* ego_seq  = (const float*)d_in[1];
  const float* ag_seq   = (const float*)d_in[2];
  const int*   ego_len  = (const int*)d_in[3];
  const int*   ag_len   = (const int*)d_in[4];
  const int*   grid_pos = (const int*)d_in[5];
  const float* sW  = (const float*)d_in[6];
  const float* sb  = (const float*)d_in[7];
  const float* Wih = (const float*)d_in[8];
  const float* Whh = (const float*)d_in[9];
  const float* bih = (const float*)d_in[10];
  const float* bhh = (const float*)d_in[11];
  const float* encW = (const float*)d_in[12];
  const float* encB = (const float*)d_in[13];
  const float* conv1W = (const float*)d_in[14];
  const float* bn1g = (const float*)d_in[15];
  const float* bn1b = (const float*)d_in[16];
  const float* conv2W = (const float*)d_in[17];
  const float* bn2g = (const float*)d_in[18];
  const float* bn2b = (const float*)d_in[19];
  const float* qWf  = (const float*)d_in[20];
  const float* kWf  = (const float*)d_in[21];
  const float* vWf  = (const float*)d_in[22];
  const float* aoW  = (const float*)d_in[23];
  const float* aoB  = (const float*)d_in[24];
  const float* clsWf = (const float*)d_in[25];
  const float* clsB  = (const float*)d_in[26];
  const float* d1Wf  = (const float*)d_in[27];
  const float* d1B   = (const float*)d_in[28];
  const float* d2Wf  = (const float*)d_in[29];
  const float* d2B   = (const float*)d_in[30];

  char* ws = (char*)d_ws;
  const size_t XP_OFF   = 0;                 // 71,303,168
  const size_t KV_OFF   = 0;                 // alias: after Xp dead
  const size_t Y2_OFF   = 29360128;          // alias inside Xp region
  const size_t Y1P_OFF  = 71303168;          // 33,554,432
  const size_t WP1_OFF  = 104857600;
  const size_t WP2_OFF  = 114884608;
  const size_t WKV_OFF  = 119603200;
  const size_t QW_OFF   = 121700352;
  const size_t AOW_OFF  = 122880000;
  const size_t CLSW_OFF = 123928576;
  const size_t D1W_OFF  = 123982976;
  const size_t D2W_OFF  = 124540032;
  const size_t GRID_OFF = 124744832;
  const size_t EGOT_OFF = 131167360;
  const size_t FEAT_OFF = 131314816;
  const size_t QBUF_OFF = 131593344;
  const size_t OBUF_OFF = 132117632;
  const size_t D1_OFF   = 132379776;
  const size_t D2_OFF   = 132445312;
  const size_t WC_OFF   = 132650112;
  const size_t BE_OFF   = 132699264;
  const size_t ENCW_OFF = 132700288;
  const size_t TMAT_OFF = 132708480;
  const size_t ST1_OFF  = 132709120;         // 4,096 (sum 512 + sumsq 512)
  const size_t ST2_OFF  = 132713216;         // 4,096

  uint16_t* XP   = (uint16_t*)(ws + XP_OFF);
  uint16_t* KV   = (uint16_t*)(ws + KV_OFF);
  uint16_t* Y2   = (uint16_t*)(ws + Y2_OFF);
  uint16_t* Y1P  = (uint16_t*)(ws + Y1P_OFF);
  uint16_t* WP1  = (uint16_t*)(ws + WP1_OFF);
  uint16_t* WP2  = (uint16_t*)(ws + WP2_OFF);
  uint16_t* WKV  = (uint16_t*)(ws + WKV_OFF);
  uint16_t* QW   = (uint16_t*)(ws + QW_OFF);
  uint16_t* AOW  = (uint16_t*)(ws + AOW_OFF);
  uint16_t* CLSW = (uint16_t*)(ws + CLSW_OFF);
  uint16_t* D1W  = (uint16_t*)(ws + D1W_OFF);
  uint16_t* D2W  = (uint16_t*)(ws + D2W_OFF);
  float*    GRIDB= (float*)(ws + GRID_OFF);
  uint16_t* EGOT = (uint16_t*)(ws + EGOT_OFF);
  uint16_t* FEAT = (uint16_t*)(ws + FEAT_OFF);
  float*    QBUF = (float*)(ws + QBUF_OFF);
  uint16_t* OBUF = (uint16_t*)(ws + OBUF_OFF);
  uint16_t* D1B  = (uint16_t*)(ws + D1_OFF);
  float*    D2B  = (float*)(ws + D2_OFF);
  uint16_t* WC   = (uint16_t*)(ws + WC_OFF);
  float*    BE   = (float*)(ws + BE_OFF);
  uint16_t* ENCWB= (uint16_t*)(ws + ENCW_OFF);
  float*    TMAT = (float*)(ws + TMAT_OFF);
  float*    ST1  = (float*)(ws + ST1_OFF);
  float*    ST2  = (float*)(ws + ST2_OFF);
  float*    outF = (float*)d_out;

  (void)hipMemsetAsync(ws + GRID_OFF, 0, 6422528, stream);
  (void)hipMemsetAsync(ws + XP_OFF,   0, 71303168, stream);
  (void)hipMemsetAsync(ws + Y1P_OFF,  0, 33554432, stream);
  (void)hipMemsetAsync(ws + ST1_OFF,  0, 8192, stream);

  // constants / weight packs
  k_lstm_prep<<<1,256,0,stream>>>(Wih,Whh,bih,bhh,sW,sb,encW, WC,BE,ENCWB, TMAT);
  k_packw<<<dim3(512,17),64,0,stream>>>(conv1W, WP1, 512, 1088);
  k_packw<<<dim3(512,8), 64,0,stream>>>(conv2W, WP2, 512, 512);
  {
    F2BJobs jb;
    jb.s[0]=kWf;  jb.d[0]=WKV;              jb.n[0]=1024*512;
    jb.s[1]=vWf;  jb.d[1]=WKV + 1024*512;   jb.n[1]=1024*512;
    jb.s[2]=qWf;  jb.d[2]=QW;               jb.n[2]=1024*576;
    jb.s[3]=aoW;  jb.d[3]=AOW;              jb.n[3]=512*1024;
    jb.s[4]=clsWf;jb.d[4]=CLSW;             jb.n[4]=25*1088;
    jb.s[5]=d1Wf; jb.d[5]=D1W;              jb.n[5]=256*1088;
    jb.s[6]=d2Wf; jb.d[6]=D2W;              jb.n[6]=400*256;
    k_f2b_multi<<<dim3(48,7),256,0,stream>>>(jb);
  }

  // encoders + scatter
  k_lstm<<<132,256,0,stream>>>(ego_seq, ag_seq, ego_len, ag_len, grid_pos,
                               WC, BE, ENCWB, encB, GRIDB, EGOT, FEAT);
  // conv input pack
  k_packx<<<dim3(128,34),256,0,stream>>>(cnn, GRIDB, XP);
  // conv1 (+stats) -> BN1 -> relu (in place, padded)
  k_conv<0><<<784,256,0,stream>>>(XP, WP1, Y1P, ST1);
  k_bnapply<1><<<3136,256,0,stream>>>(Y1P, ST1, bn1g, bn1b, 25088, 1.f/25088.f, nullptr, nullptr);
  // conv2 (+stats) -> BN2 -> relu (+ center pixel -> egoT/feat)
  k_conv<1><<<196,256,0,stream>>>(Y1P, WP2, Y2, ST2);
  k_bnapply<0><<<784,256,0,stream>>>(Y2, ST2, bn2g, bn2b, 6272, 1.f/6272.f, EGOT, FEAT);
  // k,v 1x1 convs
  k_conv<2><<<784,256,0,stream>>>(Y2, WKV, KV, nullptr);
  // q = egoT @ qW^T  (f32 out)
  k_sgemm<<<dim3(16,8),256,0,stream>>>(EGOT, 576, QW, 576, nullptr, QBUF, 1024, 1024, 576, 2);
  // attention
  k_attn<<<512,256,0,stream>>>(QBUF, KV, OBUF);
  // attn_out -> feat[:,0:512]
  k_sgemm<<<dim3(8,8),256,0,stream>>>(OBUF, 1024, AOW, 1024, aoB, FEAT, 1088, 512, 1024, 0);
  // conf -> d_out[121600:]
  k_sgemm<<<dim3(1,8),256,0,stream>>>(FEAT, 1088, CLSW, 1088, clsB, outF + 121600, 25, 25, 1088, 2);
  // dec1 (relu) -> dec2 -> traj
  k_sgemm<<<dim3(4,8),256,0,stream>>>(FEAT, 1088, D1W, 1088, d1B, D1B, 256, 256, 1088, 1);
  k_sgemm<<<dim3(7,8),256,0,stream>>>(D1B, 256, D2W, 256, d2B, D2B, 400, 400, 256, 2);
  k_traj<<<13,256,0,stream>>>(D2B, TMAT, outF);

  (void)in_sizes; (void)n_in; (void)out_size; (void)ws_size;
}